// Round 6
// baseline (88.216 us; speedup 1.0000x reference)
//
#include <hip/hip_runtime.h>
#include <math.h>

#define NB 32
#define NA 48
#define RCRf 5.2f
#define RCAf 3.5f
#define PI_F 3.14159265358979f
#define TREC 1081   // C(47,2) worst case

typedef __fp16 h2f __attribute__((ext_vector_type(2)));
static __device__ __forceinline__ unsigned pkh(float a, float b) {
    h2f v = __builtin_amdgcn_cvt_pkrtz(a, b);
    return __builtin_bit_cast(unsigned, v);
}

// closed-form triangular decode: t -> (jj<kk) among m compacted neighbors
static __device__ __forceinline__ void tri_decode(int t, int m, int T, int& jj, int& kk) {
    const int u = T - 1 - t;
    int r = (int)((sqrtf(8.0f * (float)u + 1.0f) - 1.0f) * 0.5f);
    while (r * (r + 1) / 2 > u) --r;
    while ((r + 1) * (r + 2) / 2 <= u) ++r;
    jj = m - 2 - r;
    kk = m - 1 - (u - r * (r + 1) / 2);
}

// One block per (batch, center atom). 320 threads = 5 waves, ~20 KB LDS ->
// 6 blocks/CU (wave-limited), all 1536 blocks co-resident in one round.
// ZERO atomics, 2 barriers:
//   wave0: global loads + pair pass + ballot compaction   | S2
//   all:   radial partials + unsorted triple records       | S3
//   all:   feature-owner scan of all records (broadcast reads) + store
__global__ __launch_bounds__(320)
void aev_kernel(const int* __restrict__ species, const float* __restrict__ coords,
                float* __restrict__ out)
{
    const int bid = blockIdx.x;
    const int b = bid / NA;
    const int i = bid - b * NA;
    const int tid = threadIdx.x;

    __shared__ float pd[NA], pfr[NA];
    __shared__ int   ssp[NA];
    __shared__ __align__(16) float4 cpk[NA];   // (dx,dy,dz,d) compacted RCA neighbors
    __shared__ float cfc[NA];
    __shared__ int   csp[NA];
    __shared__ int   sm;
    __shared__ float radpart[5 * 64];
    __shared__ __align__(16) uint4 rec[TREC];  // cosT f32, sinT f32, pkh(avg,w), p

    // ---- wave 0: load + pair pass + compaction (other waves go straight to S2) ----
    if (tid < 64) {
        const int j = tid;
        float dx = 0.f, dy = 0.f, dz = 0.f, d = 1.0f, fr = 0.0f, fa = 0.0f;
        int sj = 0;
        bool inA = false;
        if (j < NA) {
            const float* cb = coords + (size_t)b * NA * 3;
            const float xi = cb[3 * i], yi = cb[3 * i + 1], zi = cb[3 * i + 2];
            dx = cb[3 * j] - xi; dy = cb[3 * j + 1] - yi; dz = cb[3 * j + 2] - zi;
            d = sqrtf(dx * dx + dy * dy + dz * dz);
            sj = species[b * NA + j];
            if (j != i && d <= RCRf) fr = 0.5f * __cosf((PI_F / RCRf) * d) + 0.5f;
            if (j != i && d <= RCAf) { inA = true; fa = 0.5f * __cosf((PI_F / RCAf) * d) + 0.5f; }
            pd[j] = d; pfr[j] = fr; ssp[j] = sj;
        }
        const unsigned long long mask = __ballot(inA);
        if (inA) {
            const int pos = (int)__popcll(mask & ((1ull << j) - 1ull));
            cpk[pos] = make_float4(dx, dy, dz, d);
            cfc[pos] = fa; csp[pos] = sj;
        }
        if (j == 0) sm = (int)__popcll(mask);
    }
    __syncthreads();                                                  // S2

    const int m = sm;
    const int T = m * (m - 1) / 2;

    // ---- radial partials (broadcast LDS reads, register acc) ----
    {
        const int f = tid & 63, seg = tid >> 6;
        const int s = f >> 4, r = f & 15;
        const float shf = 0.9f + 0.26875f * (float)r;
        float acc = 0.0f;
        const int j0 = seg * 10, j1 = min(NA, j0 + 10);
        for (int j = j0; j < j1; ++j) {
            const float fr = pfr[j];
            if (fr != 0.0f) {
                const float u = pd[j] - shf;
                const float v = 0.25f * __expf(-16.0f * u * u) * fr;
                acc += (ssp[j] == s) ? v : 0.0f;
            }
        }
        radpart[seg * 64 + f] = acc;
    }

    // ---- produce unsorted triple records (no atomics: slot = t) ----
    for (int t = tid; t < T; t += 320) {
        int jj, kk; tri_decode(t, m, T, jj, kk);
        const float4 qj = cpk[jj];
        const float4 qk = cpk[kk];
        const float dot = qj.x * qk.x + qj.y * qk.y + qj.z * qk.z;
        const float cosT = 0.95f * dot * __frcp_rn(qj.w * qk.w);
        const float sinT = sqrtf(fmaxf(1.0f - cosT * cosT, 0.0f));
        const float avg = 0.5f * (qj.w + qk.w);
        const float w = 2.0f * cfc[jj] * cfc[kk];
        const int s1 = csp[jj], s2 = csp[kk];
        const int lo = min(s1, s2), hi = max(s1, s2);
        const int p = (lo * (9 - lo)) / 2 + (hi - lo);
        uint4 r;
        r.x = __float_as_uint(cosT);
        r.y = __float_as_uint(sinT);
        r.z = pkh(avg, w);
        r.w = (unsigned)p;
        rec[t] = r;                                    // ds_write_b128
    }
    __syncthreads();                                                  // S3

    // ---- consume: thread owns feature (p,a,z), scans all T records ----
    const int pmine = tid >> 5;
    const float CZt[8] = { 0.98078528f, 0.83146961f, 0.55557023f, 0.19509032f,
                          -0.19509032f,-0.55557023f,-0.83146961f,-0.98078528f };
    const float SZt[8] = { 0.19509032f, 0.55557023f, 0.83146961f, 0.98078528f,
                           0.98078528f, 0.83146961f, 0.55557023f, 0.19509032f };
    const float cz = CZt[tid & 7], sz = SZt[tid & 7];
    const float sa = 0.9f + 0.65f * (float)((tid >> 3) & 3);
    float acc_a = 0.0f;
    for (int t = 0; t < T; ++t) {
        const uint4 r = rec[t];                        // broadcast ds_read_b128
        if ((int)r.w == pmine) {
            const float cosT = __uint_as_float(r.x);
            const float sinT = __uint_as_float(r.y);
            const h2f aw = __builtin_bit_cast(h2f, r.z);
            const float avg = (float)aw.x, w = (float)aw.y;
            const float base = 0.5f + 0.5f * (cosT * cz + sinT * sz);
            const float b2 = base * base, b4 = b2 * b2, b8 = b4 * b4, b16 = b8 * b8;
            const float u = avg - sa;
            acc_a += w * __expf(-8.0f * u * u) * (b16 * b16);
        }
    }

    // ---- output ----
    float* op = out + NB * NA + (size_t)(b * NA + i) * 384;
    if (tid < 64) {
        op[tid] = radpart[tid] + radpart[64 + tid] + radpart[128 + tid] +
                  radpart[192 + tid] + radpart[256 + tid];
    }
    op[64 + tid] = acc_a;
    if (tid == 0) out[b * NA + i] = (float)ssp[i];
}

extern "C" void kernel_launch(void* const* d_in, const int* in_sizes, int n_in,
                              void* d_out, int out_size, void* d_ws, size_t ws_size,
                              hipStream_t stream) {
    const int*   species = (const int*)d_in[0];
    const float* coords  = (const float*)d_in[1];
    float*       out     = (float*)d_out;
    aev_kernel<<<NB * NA, 320, 0, stream>>>(species, coords, out);
}

// Round 7
// 69.266 us; speedup vs baseline: 1.2736x; 1.2736x over previous
//
#include <hip/hip_runtime.h>
#include <math.h>

#define NB 32
#define NA 48
#define RCRf 5.2f
#define RCAf 3.5f
#define PI_F 3.14159265358979f
#define TREC 1081   // C(47,2) worst case

typedef __fp16 h2f __attribute__((ext_vector_type(2)));
static __device__ __forceinline__ unsigned pkh(float a, float b) {
    h2f v = __builtin_amdgcn_cvt_pkrtz(a, b);
    return __builtin_bit_cast(unsigned, v);
}

// closed-form triangular decode: t -> (jj<kk) among m compacted neighbors
static __device__ __forceinline__ void tri_decode(int t, int m, int T, int& jj, int& kk) {
    const int u = T - 1 - t;
    int r = (int)((sqrtf(8.0f * (float)u + 1.0f) - 1.0f) * 0.5f);
    while (r * (r + 1) / 2 > u) --r;
    while ((r + 1) * (r + 2) / 2 <= u) ++r;
    jj = m - 2 - r;
    kk = m - 1 - (u - r * (r + 1) / 2);
}

// One block per (batch, center atom). 320 threads = 5 waves.
// vs R5/R6: THIN p-sorted records (cosT,sinT f32 + pkh(avg,w) = 16 B/triple);
// the z/a expansion happens in the consume pass, split across 320 feature
// owners (2-way broadcast b128 reads, conflict-free). LDS ~20.4 KB ->
// 6 blocks/CU (wave-limited) -> all 1536 blocks co-resident in ONE round.
__global__ __launch_bounds__(320)
void aev_kernel(const int* __restrict__ species, const float* __restrict__ coords,
                float* __restrict__ out)
{
    const int bid = blockIdx.x;
    const int b = bid / NA;
    const int i = bid - b * NA;
    const int tid = threadIdx.x;

    __shared__ float pd[NA], pfr[NA];
    __shared__ int   ssp[NA];
    __shared__ __align__(16) float4 cpk[NA];   // (dx,dy,dz,d) compacted RCA neighbors
    __shared__ float cfc[NA];
    __shared__ int   csp[NA];
    __shared__ int   sm;
    __shared__ float radpart[5 * 64];
    __shared__ __align__(16) uint4 rec[TREC];  // cosT, sinT, pkh(avg,w), (pad)
    __shared__ int   cnt[10];
    __shared__ unsigned cur[10];

    if (tid >= 256 && tid < 266) cnt[tid - 256] = 0;

    // ---- wave 0: global load + pair pass + ballot compaction ----
    if (tid < 64) {
        const int j = tid;
        float dx = 0.f, dy = 0.f, dz = 0.f, d = 1.0f, fr = 0.0f, fa = 0.0f;
        int sj = 0;
        bool inA = false;
        if (j < NA) {
            const float* cb = coords + (size_t)b * NA * 3;
            const float xi = cb[3 * i], yi = cb[3 * i + 1], zi = cb[3 * i + 2];
            dx = cb[3 * j] - xi; dy = cb[3 * j + 1] - yi; dz = cb[3 * j + 2] - zi;
            d = sqrtf(dx * dx + dy * dy + dz * dz);
            sj = species[b * NA + j];
            if (j != i && d <= RCRf) fr = 0.5f * __cosf((PI_F / RCRf) * d) + 0.5f;
            if (j != i && d <= RCAf) { inA = true; fa = 0.5f * __cosf((PI_F / RCAf) * d) + 0.5f; }
            pd[j] = d; pfr[j] = fr; ssp[j] = sj;
        }
        const unsigned long long mask = __ballot(inA);
        if (inA) {
            const int pos = (int)__popcll(mask & ((1ull << j) - 1ull));
            cpk[pos] = make_float4(dx, dy, dz, d);
            cfc[pos] = fa; csp[pos] = sj;
        }
        if (j == 0) sm = (int)__popcll(mask);
    }
    __syncthreads();                                                  // S1

    const int m = sm;
    const int T = m * (m - 1) / 2;

    // ---- radial partials (broadcast LDS reads, register acc) ----
    {
        const int f = tid & 63, seg = tid >> 6;
        const int s = f >> 4, r = f & 15;
        const float shf = 0.9f + 0.26875f * (float)r;
        float acc = 0.0f;
        const int j0 = seg * 10, j1 = min(NA, j0 + 10);
        for (int j = j0; j < j1; ++j) {
            const float fr = pfr[j];
            if (fr != 0.0f) {
                const float u = pd[j] - shf;
                const float v = 0.25f * __expf(-16.0f * u * u) * fr;
                acc += (ssp[j] == s) ? v : 0.0f;
            }
        }
        radpart[seg * 64 + f] = acc;
    }
    // ---- histogram of pair indices ----
    for (int t = tid; t < T; t += 320) {
        int jj, kk; tri_decode(t, m, T, jj, kk);
        const int s1 = csp[jj], s2 = csp[kk];
        const int lo = min(s1, s2), hi = max(s1, s2);
        const int p = (lo * (9 - lo)) / 2 + (hi - lo);
        atomicAdd(&cnt[p], 1);
    }
    __syncthreads();                                                  // S2

    // ---- all-thread redundant prefix ----
    const int pmine = tid >> 5;
    int mybase = 0, mycnt = 0, run = 0;
    #pragma unroll
    for (int p = 0; p < 10; ++p) {
        const int cp = cnt[p];
        if (p == pmine) { mybase = run; mycnt = cp; }
        if (tid < 10 && p == tid) cur[tid] = (unsigned)run;
        run += cp;
    }
    __syncthreads();                                                  // S3

    // ---- produce: thin records into p-sorted slots ----
    for (int t = tid; t < T; t += 320) {
        int jj, kk; tri_decode(t, m, T, jj, kk);
        const float4 qj = cpk[jj];
        const float4 qk = cpk[kk];
        const float dot = qj.x * qk.x + qj.y * qk.y + qj.z * qk.z;
        const float cosT = 0.95f * dot * __frcp_rn(qj.w * qk.w);
        const float sinT = sqrtf(fmaxf(1.0f - cosT * cosT, 0.0f));
        const float avg = 0.5f * (qj.w + qk.w);
        const float w = 2.0f * cfc[jj] * cfc[kk];
        const int s1 = csp[jj], s2 = csp[kk];
        const int lo = min(s1, s2), hi = max(s1, s2);
        const int p = (lo * (9 - lo)) / 2 + (hi - lo);
        const unsigned pos = atomicAdd(&cur[p], 1u);
        uint4 r;
        r.x = __float_as_uint(cosT);
        r.y = __float_as_uint(sinT);
        r.z = pkh(avg, w);
        r.w = 0u;
        rec[pos] = r;                                  // ds_write_b128
    }
    __syncthreads();                                                  // S4

    // ---- consume: thread owns feature (p,a,z), scans its p-bucket ----
    const float CZt[8] = { 0.98078528f, 0.83146961f, 0.55557023f, 0.19509032f,
                          -0.19509032f,-0.55557023f,-0.83146961f,-0.98078528f };
    const float SZt[8] = { 0.19509032f, 0.55557023f, 0.83146961f, 0.98078528f,
                           0.98078528f, 0.83146961f, 0.55557023f, 0.19509032f };
    const float cz = CZt[tid & 7], sz = SZt[tid & 7];
    const float sa = 0.9f + 0.65f * (float)((tid >> 3) & 3);
    float acc_a = 0.0f;
    for (int k = mybase; k < mybase + mycnt; ++k) {
        const uint4 r = rec[k];                        // 2-way broadcast b128
        const float cosT = __uint_as_float(r.x);
        const float sinT = __uint_as_float(r.y);
        const h2f aw = __builtin_bit_cast(h2f, r.z);
        const float avg = (float)aw.x, w = (float)aw.y;
        const float base = 0.5f + 0.5f * (cosT * cz + sinT * sz);
        const float b2 = base * base, b4 = b2 * b2, b8 = b4 * b4, b16 = b8 * b8;
        const float u = avg - sa;
        acc_a += w * __expf(-8.0f * u * u) * (b16 * b16);
    }

    // ---- output ----
    float* op = out + NB * NA + (size_t)(b * NA + i) * 384;
    if (tid < 64) {
        op[tid] = radpart[tid] + radpart[64 + tid] + radpart[128 + tid] +
                  radpart[192 + tid] + radpart[256 + tid];
    }
    op[64 + tid] = acc_a;
    if (tid == 0) out[b * NA + i] = (float)ssp[i];
}

extern "C" void kernel_launch(void* const* d_in, const int* in_sizes, int n_in,
                              void* d_out, int out_size, void* d_ws, size_t ws_size,
                              hipStream_t stream) {
    const int*   species = (const int*)d_in[0];
    const float* coords  = (const float*)d_in[1];
    float*       out     = (float*)d_out;
    aev_kernel<<<NB * NA, 320, 0, stream>>>(species, coords, out);
}

// Round 8
// 65.547 us; speedup vs baseline: 1.3458x; 1.0567x over previous
//
#include <hip/hip_runtime.h>
#include <math.h>

#define NB 32
#define NA 48
#define RCRf 5.2f
#define RCAf 3.5f
#define PI_F 3.14159265358979f
#define CMAX 1000   // triples per chunk; 1 chunk unless m >= 46 (T>1000)

typedef unsigned short ushort_t;
typedef __fp16 h2f __attribute__((ext_vector_type(2)));
static __device__ __forceinline__ unsigned pkh(float a, float b) {
    h2f v = __builtin_amdgcn_cvt_pkrtz(a, b);
    return __builtin_bit_cast(unsigned, v);
}
static __device__ __forceinline__ float uph(ushort_t u) {
    return (float)__builtin_bit_cast(__fp16, u);
}

// closed-form triangular decode: t -> (jj<kk) among m compacted neighbors
static __device__ __forceinline__ void tri_decode(int t, int m, int T, int& jj, int& kk) {
    const int u = T - 1 - t;
    int r = (int)((sqrtf(8.0f * (float)u + 1.0f) - 1.0f) * 0.5f);
    while (r * (r + 1) / 2 > u) --r;
    while ((r + 1) * (r + 2) / 2 <= u) ++r;
    jj = m - 2 - r;
    kk = m - 1 - (u - r * (r + 1) / 2);
}

// One block per (batch, center atom). 320 threads = 5 waves.
// R5's op-minimal produce-heavy fp16 records + 6 blocks/CU occupancy:
// LDS ~26.5 KB <= 163840/6 -> all 1536 blocks co-resident in ONE round.
// 4 barriers on the single-chunk path (the only path real data takes).
__global__ __launch_bounds__(320)
void aev_kernel(const int* __restrict__ species, const float* __restrict__ coords,
                float* __restrict__ out)
{
    const int bid = blockIdx.x;
    const int b = bid / NA;
    const int i = bid - b * NA;
    const int tid = threadIdx.x;

    __shared__ float pd[NA], pfr[NA];
    __shared__ int   ssp[NA];
    __shared__ __align__(16) float4 cpk[NA];   // (dx,dy,dz,d) compacted RCA neighbors
    __shared__ float cfc[NA];
    __shared__ int   csp[NA];
    __shared__ int   sm;
    __shared__ float radpart[5 * 64];
    __shared__ __align__(16) ushort_t f1h[CMAX * 8];   // fp16 f1[z], 16 B/triple
    __shared__ __align__(16) ushort_t w2h[CMAX * 4];   // fp16 w*f2[a], 8 B/triple
    __shared__ int   cnt[10];
    __shared__ unsigned cur[10];

    if (tid >= 256 && tid < 266) cnt[tid - 256] = 0;

    // ---- wave 0: global load + pair pass + ballot compaction ----
    if (tid < 64) {
        const int j = tid;
        float dx = 0.f, dy = 0.f, dz = 0.f, d = 1.0f, fr = 0.0f, fa = 0.0f;
        int sj = 0;
        bool inA = false;
        if (j < NA) {
            const float* cb = coords + (size_t)b * NA * 3;
            const float xi = cb[3 * i], yi = cb[3 * i + 1], zi = cb[3 * i + 2];
            dx = cb[3 * j] - xi; dy = cb[3 * j + 1] - yi; dz = cb[3 * j + 2] - zi;
            d = sqrtf(dx * dx + dy * dy + dz * dz);
            sj = species[b * NA + j];
            if (j != i && d <= RCRf) fr = 0.5f * __cosf((PI_F / RCRf) * d) + 0.5f;
            if (j != i && d <= RCAf) { inA = true; fa = 0.5f * __cosf((PI_F / RCAf) * d) + 0.5f; }
            pd[j] = d; pfr[j] = fr; ssp[j] = sj;
        }
        const unsigned long long mask = __ballot(inA);
        if (inA) {
            const int pos = (int)__popcll(mask & ((1ull << j) - 1ull));
            cpk[pos] = make_float4(dx, dy, dz, d);
            cfc[pos] = fa; csp[pos] = sj;
        }
        if (j == 0) sm = (int)__popcll(mask);
    }
    __syncthreads();                                                  // S1

    const int m = sm;
    const int T = m * (m - 1) / 2;
    const int nchunks = (T + CMAX - 1) / CMAX;   // ==1 unless m>=46

    // ---- radial partials (broadcast LDS reads, register acc) ----
    {
        const int f = tid & 63, seg = tid >> 6;
        const int s = f >> 4, r = f & 15;
        const float shf = 0.9f + 0.26875f * (float)r;
        float acc = 0.0f;
        const int j0 = seg * 10, j1 = min(NA, j0 + 10);
        for (int j = j0; j < j1; ++j) {
            const float fr = pfr[j];
            if (fr != 0.0f) {
                const float u = pd[j] - shf;
                const float v = 0.25f * __expf(-16.0f * u * u) * fr;
                acc += (ssp[j] == s) ? v : 0.0f;
            }
        }
        radpart[seg * 64 + f] = acc;
    }
    // ---- histogram of pair indices (chunk 0) ----
    {
        const int cT = min(CMAX, T);
        for (int t = tid; t < cT; t += 320) {
            int jj, kk; tri_decode(t, m, T, jj, kk);
            const int s1 = csp[jj], s2 = csp[kk];
            const int lo = min(s1, s2), hi = max(s1, s2);
            const int p = (lo * (9 - lo)) / 2 + (hi - lo);
            atomicAdd(&cnt[p], 1);
        }
    }
    __syncthreads();                                                  // S2

    const int pmine = tid >> 5, amine = (tid >> 3) & 3, zmine = tid & 7;
    const float CZ[8] = { 0.98078528f, 0.83146961f, 0.55557023f, 0.19509032f,
                         -0.19509032f,-0.55557023f,-0.83146961f,-0.98078528f };
    const float SZ[8] = { 0.19509032f, 0.55557023f, 0.83146961f, 0.98078528f,
                          0.98078528f, 0.83146961f, 0.55557023f, 0.19509032f };
    const float SA[4] = { 0.9f, 1.55f, 2.2f, 2.85f };
    float acc_a = 0.0f;

    for (int c = 0; c < nchunks; ++c) {
        const int t0 = c * CMAX;
        const int cT = min(CMAX, T - t0);

        // all-thread redundant prefix over this chunk's histogram
        int mybase = 0, mycnt = 0, run = 0;
        #pragma unroll
        for (int p = 0; p < 10; ++p) {
            const int cp = cnt[p];
            if (p == pmine) { mybase = run; mycnt = cp; }
            if (tid < 10 && p == tid) cur[tid] = (unsigned)run;
            run += cp;
        }
        __syncthreads();                                              // S3

        // produce: full fp16 records into p-sorted slots (shared math ONCE)
        for (int t = tid; t < cT; t += 320) {
            int jj, kk; tri_decode(t0 + t, m, T, jj, kk);
            const float4 qj = cpk[jj];      // ds_read_b128
            const float4 qk = cpk[kk];      // ds_read_b128
            const float dot = qj.x * qk.x + qj.y * qk.y + qj.z * qk.z;
            const float cosT = 0.95f * dot * __frcp_rn(qj.w * qk.w);
            const float sinT = sqrtf(fmaxf(1.0f - cosT * cosT, 0.0f));
            const float avg = 0.5f * (qj.w + qk.w);
            const float w = 2.0f * cfc[jj] * cfc[kk];
            const int s1 = csp[jj], s2 = csp[kk];
            const int lo = min(s1, s2), hi = max(s1, s2);
            const int p = (lo * (9 - lo)) / 2 + (hi - lo);

            float f1v[8];
            #pragma unroll
            for (int z = 0; z < 8; ++z) {
                const float base = 0.5f + 0.5f * (cosT * CZ[z] + sinT * SZ[z]);
                const float b2 = base * base, b4 = b2 * b2, b8 = b4 * b4, b16 = b8 * b8;
                f1v[z] = b16 * b16;   // base^32
            }
            float w2v[4];
            #pragma unroll
            for (int a = 0; a < 4; ++a) {
                const float u = avg - SA[a];
                w2v[a] = w * __expf(-8.0f * u * u);
            }
            const unsigned pos = atomicAdd(&cur[p], 1u);
            uint4 rf;
            rf.x = pkh(f1v[0], f1v[1]); rf.y = pkh(f1v[2], f1v[3]);
            rf.z = pkh(f1v[4], f1v[5]); rf.w = pkh(f1v[6], f1v[7]);
            ((uint4*)f1h)[pos] = rf;                       // ds_write_b128
            uint2 rw;
            rw.x = pkh(w2v[0], w2v[1]); rw.y = pkh(w2v[2], w2v[3]);
            ((uint2*)w2h)[pos] = rw;                       // ds_write_b64
        }
        __syncthreads();                                              // S4

        // consume: thread owns (p,a,z), scans its p-bucket (2 u16 reads + fma)
        for (int k = mybase; k < mybase + mycnt; ++k)
            acc_a += uph(w2h[k * 4 + amine]) * uph(f1h[k * 8 + zmine]);

        // rare fallback: prep next chunk (m >= 46 only)
        if (c + 1 < nchunks) {
            __syncthreads();
            if (tid < 10) cnt[tid] = 0;
            __syncthreads();
            const int n0 = (c + 1) * CMAX;
            const int nT = min(CMAX, T - n0);
            for (int t = tid; t < nT; t += 320) {
                int jj, kk; tri_decode(n0 + t, m, T, jj, kk);
                const int s1 = csp[jj], s2 = csp[kk];
                const int lo = min(s1, s2), hi = max(s1, s2);
                const int p = (lo * (9 - lo)) / 2 + (hi - lo);
                atomicAdd(&cnt[p], 1);
            }
            __syncthreads();
        }
    }

    // ---- output (radpart fenced by S2) ----
    float* op = out + NB * NA + (size_t)(b * NA + i) * 384;
    if (tid < 64) {
        op[tid] = radpart[tid] + radpart[64 + tid] + radpart[128 + tid] +
                  radpart[192 + tid] + radpart[256 + tid];
    }
    op[64 + tid] = acc_a;
    if (tid == 0) out[b * NA + i] = (float)ssp[i];
}

extern "C" void kernel_launch(void* const* d_in, const int* in_sizes, int n_in,
                              void* d_out, int out_size, void* d_ws, size_t ws_size,
                              hipStream_t stream) {
    const int*   species = (const int*)d_in[0];
    const float* coords  = (const float*)d_in[1];
    float*       out     = (float*)d_out;
    aev_kernel<<<NB * NA, 320, 0, stream>>>(species, coords, out);
}